// Round 4
// baseline (385.511 us; speedup 1.0000x reference)
//
#include <hip/hip_runtime.h>
#include <cmath>

// GaussCRF on MI355X — round 4.
// B=2, C=21, H=W=512, blur=4 -> h=w=128, K=11 (121 shifts), 5 iterations.
//
// vs round 3: msg_k + combine_k fused into one iter_k per iteration.
//  * Block = 8x8 pooled tile. msg computed on a 10x10 halo'd position set
//    (edge positions coordinate-clamped, which reproduces the bilinear tap
//    clamp) into LDS; bilinear 4x upsample + (1-w)*lg + w*mu + softmax +
//    4x4 pool run in the same block. msg NEVER touches global memory.
//  * p double-buffered across iterations (producer/consumer now same kernel).
//  * 8 dispatches total (was 13). LDS 48 KB -> 3 blocks/CU, grid 512 blocks.

#define BB 2
#define CC 21
#define HH 512
#define WW 512
#define HP 128
#define WP 128
#define KF 11
#define SPAN 5
#define NB 121
#define NITER 5
#define PLF (HH*WW)
#define PLP (HP*WP)
#define TCH 24    // padded channel stride (16B-aligned float4 reads)

__global__ void pool_img_k(const float* __restrict__ img,
                           const float* __restrict__ col_schan,
                           float* __restrict__ cf) {
    int idx = blockIdx.x * blockDim.x + threadIdx.x;
    if (idx >= BB*3*PLP) return;
    int Y  = idx & (WP-1);
    int X  = (idx >> 7) & (HP-1);
    int bc = idx >> 14;
    const float* base = img + ((size_t)bc*HH + X*4)*WW + Y*4;
    float s = 0.f;
    #pragma unroll
    for (int i = 0; i < 4; ++i)
        #pragma unroll
        for (int j = 0; j < 4; ++j)
            s += base[i*WW + j];
    cf[idx] = s * (1.f/16.f) * col_schan[0];
}

// one thread per (b, ij, X, Y); g layout [b][ij][X][Y]
__global__ void gauss_k(const float* __restrict__ cf,
                        const float* __restrict__ pos_sdims,
                        const float* __restrict__ pos_compat,
                        const float* __restrict__ col_compat,
                        float* __restrict__ g) {
    int idx = blockIdx.x * blockDim.x + threadIdx.x;
    if (idx >= BB*NB*PLP) return;
    int xy = idx & (PLP-1);
    int t  = idx >> 14;
    int ij = t % NB;
    int b  = t / NB;
    int Y = xy & (WP-1);
    int X = xy >> 7;
    int di = ij / KF - SPAN;
    int dj = ij % KF - SPAN;
    int Xn = X + di, Yn = Y + dj;
    float val = 0.f;
    if (Xn >= 0 && Xn < HP && Yn >= 0 && Yn < WP) {
        const float* cb = cf + (size_t)b*3*PLP;
        int o0 = xy, o = Xn*WP + Yn;
        float d0 = cb[o]         - cb[o0];
        float d1 = cb[PLP + o]   - cb[PLP + o0];
        float d2 = cb[2*PLP + o] - cb[2*PLP + o0];
        float cd2 = d0*d0 + d1*d1 + d2*d2;
        float ps  = 4.f * pos_sdims[0];
        float pd2 = ps*ps * (float)(di*di + dj*dj);
        val = pos_compat[0] * expf(-0.5f*pd2) + col_compat[0] * expf(-0.5f*cd2);
    }
    g[idx] = val;
}

// p0 = 4x4 pool of log_softmax(unary)
__global__ __launch_bounds__(256) void init_p_k(const float* __restrict__ unary,
                                                float* __restrict__ p) {
    int b  = blockIdx.z;
    int tx = blockIdx.y, ty = blockIdx.x;     // 32 x 32 tiles of 16x16
    int l  = threadIdx.x;
    int row = l >> 4, col = l & 15;
    int x = tx*16 + row, y = ty*16 + col;
    size_t base = (size_t)b*CC*PLF + (size_t)x*WW + y;
    float v[CC];
    float m = -1e30f;
    #pragma unroll
    for (int c = 0; c < CC; ++c) { v[c] = unary[base + (size_t)c*PLF]; m = fmaxf(m, v[c]); }
    float s = 0.f;
    #pragma unroll
    for (int c = 0; c < CC; ++c) s += expf(v[c]-m);
    float ls = m + logf(s);
    int X = tx*4 + (row>>2), Y = ty*4 + (col>>2);
    size_t pb = (size_t)b*CC*PLP + (size_t)X*WP + Y;
    bool wr = (l & 51) == 0;                  // lane bits {0,1,4,5} == 0
    #pragma unroll
    for (int c = 0; c < CC; ++c) {
        float sm = v[c] - ls;
        sm += __shfl_xor(sm, 1);
        sm += __shfl_xor(sm, 2);
        sm += __shfl_xor(sm, 16);
        sm += __shfl_xor(sm, 32);
        if (wr) p[pb + (size_t)c*PLP] = sm * (1.f/16.f);
    }
}

// Fused per-iteration kernel. Block = 8x8 pooled tile; grid (16,16,BB).
__global__ __launch_bounds__(256) void iter_k(const float* __restrict__ g,
                                              const float* __restrict__ p,
                                              const float* __restrict__ unary,
                                              const float* __restrict__ weight,
                                              float* __restrict__ pnew,
                                              float* __restrict__ pred,
                                              int last) {
    int b  = blockIdx.z;
    int tx = blockIdx.y, ty = blockIdx.x;     // 0..15 each
    int tid = threadIdx.x;
    int X0 = tx*8, Y0 = ty*8;
    __shared__ float pt[20][20][TCH];         // 38.4 KB : p tile + halo 6
    __shared__ float ms[100*TCH];             // 9.6 KB  : msg on 10x10 halo'd positions
    const float* pb = p + (size_t)b*CC*PLP;

    // ---- stage p tile (rows/cols X0-6 .. X0+13), zero outside image ----
    for (int e = tid; e < CC*400; e += 256) {
        int c  = e / 400;
        int rr = (e % 400) / 20;
        int cl = e % 20;
        int gX = X0 - 6 + rr, gY = Y0 - 6 + cl;
        float v = 0.f;
        if (gX >= 0 && gX < HP && gY >= 0 && gY < WP)
            v = pb[(size_t)c*PLP + gX*WP + gY];
        pt[rr][cl][c] = v;
    }
    __syncthreads();

    // ---- msg on 10x10 positions (1-halo, coord-clamped), 2 ij-halves ----
    float acc[CC];
    int half = tid / 100;                     // 0,1 active; 2 idle
    int pp   = tid % 100;
    if (half < 2) {
        int px = pp / 10, py = pp % 10;
        int Xc = X0 - 1 + px; Xc = Xc < 0 ? 0 : (Xc > HP-1 ? HP-1 : Xc);
        int Yc = Y0 - 1 + py; Yc = Yc < 0 ? 0 : (Yc > WP-1 ? WP-1 : Yc);
        int lx = Xc - X0 + 6, ly = Yc - Y0 + 6;
        const float* gq = g + (size_t)b*NB*PLP + (size_t)Xc*WP + Yc;
        #pragma unroll
        for (int c = 0; c < CC; ++c) acc[c] = 0.f;
        int ij0 = half ? 61 : 0;
        int nij = half ? 60 : 61;
        #pragma unroll 4
        for (int k = 0; k < nij; ++k) {
            int ij = ij0 + k;
            int di = ij / KF, dj = ij - di*KF;
            float gv = gq[(size_t)ij*PLP];
            const float* sp = &pt[lx + di - 5][ly + dj - 5][0];
            const float4* qv = (const float4*)sp;
            float4 q0 = qv[0], q1 = qv[1], q2 = qv[2], q3 = qv[3], q4 = qv[4];
            float  q5 = sp[20];
            acc[0]  = fmaf(gv, q0.x, acc[0]);  acc[1]  = fmaf(gv, q0.y, acc[1]);
            acc[2]  = fmaf(gv, q0.z, acc[2]);  acc[3]  = fmaf(gv, q0.w, acc[3]);
            acc[4]  = fmaf(gv, q1.x, acc[4]);  acc[5]  = fmaf(gv, q1.y, acc[5]);
            acc[6]  = fmaf(gv, q1.z, acc[6]);  acc[7]  = fmaf(gv, q1.w, acc[7]);
            acc[8]  = fmaf(gv, q2.x, acc[8]);  acc[9]  = fmaf(gv, q2.y, acc[9]);
            acc[10] = fmaf(gv, q2.z, acc[10]); acc[11] = fmaf(gv, q2.w, acc[11]);
            acc[12] = fmaf(gv, q3.x, acc[12]); acc[13] = fmaf(gv, q3.y, acc[13]);
            acc[14] = fmaf(gv, q3.z, acc[14]); acc[15] = fmaf(gv, q3.w, acc[15]);
            acc[16] = fmaf(gv, q4.x, acc[16]); acc[17] = fmaf(gv, q4.y, acc[17]);
            acc[18] = fmaf(gv, q4.z, acc[18]); acc[19] = fmaf(gv, q4.w, acc[19]);
            acc[20] = fmaf(gv, q5,   acc[20]);
        }
    }
    __syncthreads();
    if (half == 1) {
        #pragma unroll
        for (int c = 0; c < CC; ++c) ms[pp*TCH + c] = acc[c];
    }
    __syncthreads();
    if (half == 0) {
        #pragma unroll
        for (int c = 0; c < CC; ++c) ms[pp*TCH + c] += acc[c];
    }
    __syncthreads();

    // ---- combine: bilinear up + (1-w)*lg + w*mu (+ softmax + pool) ----
    float wt = weight[0], uw = 1.f - wt;      // UNARY_WEIGHT = 1.0
    int row = tid >> 4, col = tid & 15;
    int rs = row & 3, q  = row >> 2;
    int cs = col & 3, qc = col >> 2;
    // fx per (x%4): {0.625, 0.875, 0.125, 0.375}
    float fx = (rs == 0) ? 0.625f : (rs == 1) ? 0.875f : (rs == 2) ? 0.125f : 0.375f;
    float fy = (cs == 0) ? 0.625f : (cs == 1) ? 0.875f : (cs == 2) ? 0.125f : 0.375f;
    float w00 = (1.f-fx)*(1.f-fy), w01 = (1.f-fx)*fy;
    float w10 = fx*(1.f-fy),       w11 = fx*fy;
    bool wr = (tid & 51) == 0;
    #pragma unroll
    for (int st = 0; st < 4; ++st) {
        int sr = st >> 1, sc = st & 1;
        int x = X0*4 + sr*16 + row;
        int y = Y0*4 + sc*16 + col;
        int im = sr*4 + q  + (rs >> 1);       // 0..8 in the 10-wide halo'd ms
        int jm = sc*4 + qc + (cs >> 1);
        const float* m00 = &ms[(im*10 + jm)*TCH];
        const float* m01 = m00 + TCH;
        const float* m10 = m00 + 10*TCH;
        const float* m11 = m10 + TCH;
        size_t base = (size_t)b*CC*PLF + (size_t)x*WW + y;
        float v[CC];
        float mx = -1e30f;
        #pragma unroll
        for (int c = 0; c < CC; ++c) { v[c] = unary[base + (size_t)c*PLF]; mx = fmaxf(mx, v[c]); }
        float s = 0.f;
        #pragma unroll
        for (int c = 0; c < CC; ++c) s += expf(v[c]-mx);
        float ls = mx + logf(s);
        #pragma unroll
        for (int c = 0; c < CC; ++c) {
            float mu = w00*m00[c] + w01*m01[c] + w10*m10[c] + w11*m11[c];
            v[c] = uw*(v[c]-ls) + wt*mu;
        }
        if (!last) {
            float mm = -1e30f;
            #pragma unroll
            for (int c = 0; c < CC; ++c) mm = fmaxf(mm, v[c]);
            float ss = 0.f;
            #pragma unroll
            for (int c = 0; c < CC; ++c) { float e = expf(v[c]-mm); v[c] = e; ss += e; }
            float inv = 1.f/ss;
            int X = X0 + sr*4 + q, Y = Y0 + sc*4 + qc;
            size_t pw = (size_t)b*CC*PLP + (size_t)X*WP + Y;
            #pragma unroll
            for (int c = 0; c < CC; ++c) {
                float sm = v[c]*inv;
                sm += __shfl_xor(sm, 1);
                sm += __shfl_xor(sm, 2);
                sm += __shfl_xor(sm, 16);
                sm += __shfl_xor(sm, 32);
                if (wr) pnew[pw + (size_t)c*PLP] = sm * (1.f/16.f);
            }
        } else {
            #pragma unroll
            for (int c = 0; c < CC; ++c)
                pred[base + (size_t)c*PLF] = v[c];
        }
    }
}

extern "C" void kernel_launch(void* const* d_in, const int* in_sizes, int n_in,
                              void* d_out, int out_size, void* d_ws, size_t ws_size,
                              hipStream_t stream) {
    const float* unary      = (const float*)d_in[0];
    const float* img        = (const float*)d_in[1];
    const float* pos_sdims  = (const float*)d_in[2];
    const float* col_schan  = (const float*)d_in[3];
    const float* pos_compat = (const float*)d_in[4];
    const float* col_compat = (const float*)d_in[5];
    const float* weight     = (const float*)d_in[6];
    float* pred = (float*)d_out;
    float* ws   = (float*)d_ws;

    size_t o = 0;
    float* g   = ws + o;  o += (size_t)BB*NB*PLP;   // 15.9 MB
    float* cf  = ws + o;  o += (size_t)BB*3*PLP;    // 0.4 MB
    float* pA  = ws + o;  o += (size_t)BB*CC*PLP;   // 2.75 MB
    float* pB  = ws + o;                            // 2.75 MB
    float* pbuf[2] = {pA, pB};

    const int TB = 256;
    hipLaunchKernelGGL(pool_img_k, dim3((BB*3*PLP+TB-1)/TB), dim3(TB), 0, stream,
                       img, col_schan, cf);
    hipLaunchKernelGGL(gauss_k, dim3((BB*NB*PLP+TB-1)/TB), dim3(TB), 0, stream,
                       cf, pos_sdims, pos_compat, col_compat, g);
    hipLaunchKernelGGL(init_p_k, dim3(32, 32, BB), dim3(256), 0, stream,
                       unary, pA);
    for (int it = 0; it < NITER; ++it) {
        hipLaunchKernelGGL(iter_k, dim3(16, 16, BB), dim3(256), 0, stream,
                           g, pbuf[it & 1], unary, weight, pbuf[(it + 1) & 1],
                           pred, (it == NITER-1) ? 1 : 0);
    }
}

// Round 7
// 318.403 us; speedup vs baseline: 1.2108x; 1.2108x over previous
//
#include <hip/hip_runtime.h>
#include <cmath>

// GaussCRF on MI355X — round 7.
// B=2, C=21, H=W=512, blur=4 -> h=w=128, K=11 (121 shifts), 5 iterations.
//
// Post-mortem r5/r6: the CRF iteration amplifies injected noise ~1000x in
// high-affinity spots (fp32 baseline absmax 0.25 from 1e-7 rounding), so any
// fp16 in the iterated path fails. ALL fp32 this round; attack latency and
// instruction count instead:
//  * msg_k: p packed [X][Y][24]f32; LDS tile [18][18][28] (stride 28 -> 2-way
//    bank aliasing only = free); 6x ds_read_b128 + 24 FMA per tap; 64-thr
//    blocks, 512-block grid (was 256x256 = 1 block/CU -> latency-starved).
//  * combine_k: 2 pixels/thread (float2 loads of unary), pixel-pair shares
//    the 4 bilinear taps; softmax+4x4 pool via shfl; writes packed p.
//    1024 blocks, 16 waves/CU -> streams unary at high BW.
//  * per-iter HBM floor ~60 MB (unary 44 + g 16); L3 shown not to retain
//    across dispatches (r4: 78 MB FETCH).

#define BB 2
#define CC 21
#define HH 512
#define WW 512
#define HP 128
#define WP 128
#define KF 11
#define SPAN 5
#define NB 121
#define NITER 5
#define PLF (HH*WW)
#define PLP (HP*WP)
#define PC 24      // packed channel stride (floats), 96 B = 6 x float4
#define LSTR 28    // LDS channel stride in msg tile (2-way bank aliasing)

__global__ void pool_img_k(const float* __restrict__ img,
                           const float* __restrict__ col_schan,
                           float* __restrict__ cf) {
    int idx = blockIdx.x * blockDim.x + threadIdx.x;
    if (idx >= BB*3*PLP) return;
    int Y  = idx & (WP-1);
    int X  = (idx >> 7) & (HP-1);
    int bc = idx >> 14;
    const float* base = img + ((size_t)bc*HH + X*4)*WW + Y*4;
    float s = 0.f;
    #pragma unroll
    for (int i = 0; i < 4; ++i)
        #pragma unroll
        for (int j = 0; j < 4; ++j)
            s += base[i*WW + j];
    cf[idx] = s * (1.f/16.f) * col_schan[0];
}

// one thread per (b, ij, X, Y); g layout [b][ij][X][Y] fp32
__global__ void gauss_k(const float* __restrict__ cf,
                        const float* __restrict__ pos_sdims,
                        const float* __restrict__ pos_compat,
                        const float* __restrict__ col_compat,
                        float* __restrict__ g) {
    int idx = blockIdx.x * blockDim.x + threadIdx.x;
    if (idx >= BB*NB*PLP) return;
    int xy = idx & (PLP-1);
    int t  = idx >> 14;
    int ij = t % NB;
    int b  = t / NB;
    int Y = xy & (WP-1);
    int X = xy >> 7;
    int di = ij / KF - SPAN;
    int dj = ij % KF - SPAN;
    int Xn = X + di, Yn = Y + dj;
    float val = 0.f;
    if (Xn >= 0 && Xn < HP && Yn >= 0 && Yn < WP) {
        const float* cb = cf + (size_t)b*3*PLP;
        int o0 = xy, o = Xn*WP + Yn;
        float d0 = cb[o]         - cb[o0];
        float d1 = cb[PLP + o]   - cb[PLP + o0];
        float d2 = cb[2*PLP + o] - cb[2*PLP + o0];
        float cd2 = d0*d0 + d1*d1 + d2*d2;
        float ps  = 4.f * pos_sdims[0];
        float pd2 = ps*ps * (float)(di*di + dj*dj);
        val = pos_compat[0] * expf(-0.5f*pd2) + col_compat[0] * expf(-0.5f*cd2);
    }
    g[idx] = val;
}

// p0 = 4x4 pool of log_softmax(unary), packed fp32 [b][X][Y][24].
// grid (16, 32, BB): block covers 16 rows x 32 cols of full-res pixels.
__global__ __launch_bounds__(256) void init_p_k(const float* __restrict__ unary,
                                                float* __restrict__ p) {
    int b = blockIdx.z, tx = blockIdx.y, ty = blockIdx.x;
    int t = threadIdx.x;
    int row = t >> 4, c2 = t & 15;
    int x = tx*16 + row, y = ty*32 + 2*c2;
    size_t base = (size_t)b*CC*PLF + (size_t)x*WW + y;
    float va[CC], vb[CC];
    float ma = -1e30f, mb = -1e30f;
    #pragma unroll
    for (int c = 0; c < CC; ++c) {
        float2 u = *(const float2*)(unary + base + (size_t)c*PLF);
        va[c] = u.x; vb[c] = u.y;
        ma = fmaxf(ma, u.x); mb = fmaxf(mb, u.y);
    }
    float sa = 0.f, sb = 0.f;
    #pragma unroll
    for (int c = 0; c < CC; ++c) { sa += expf(va[c]-ma); sb += expf(vb[c]-mb); }
    float lsa = ma + logf(sa), lsb = mb + logf(sb);
    float out[PC];
    #pragma unroll
    for (int c = 0; c < PC; ++c) out[c] = 0.f;
    #pragma unroll
    for (int c = 0; c < CC; ++c) {
        float sm = (va[c]-lsa) + (vb[c]-lsb);
        sm += __shfl_xor(sm, 1);
        sm += __shfl_xor(sm, 16);
        sm += __shfl_xor(sm, 32);
        out[c] = sm * (1.f/16.f);
    }
    int lane = t & 63;
    if ((lane & 49) == 0) {                  // bits {0,4,5} == 0
        int X = tx*4 + (t >> 6), Y = ty*8 + (c2 >> 1);
        float4* dst = (float4*)(p + ((size_t)(b*HP + X)*WP + Y)*PC);
        const float4* src = (const float4*)out;
        dst[0]=src[0]; dst[1]=src[1]; dst[2]=src[2];
        dst[3]=src[3]; dst[4]=src[4]; dst[5]=src[5];
    }
}

// msg[b,c,X,Y] = sum_ij g[b,ij,X,Y] * p_packed[b,X+di-5,Y+dj-5,c]
// block = 64 thr = 8x8 positions; grid (16,16,BB) = 512 blocks.
__global__ __launch_bounds__(64) void msg_k(const float* __restrict__ g,
                                            const float* __restrict__ p,
                                            float* __restrict__ msg) {
    int b = blockIdx.z, tx = blockIdx.y, ty = blockIdx.x;
    int t = threadIdx.x;
    int x = t >> 3, y = t & 7;
    __shared__ __align__(16) float pt[18*18*LSTR];   // 36.3 KB
    int X0 = tx*8 - SPAN, Y0 = ty*8 - SPAN;
    const float4* pg = (const float4*)(p + (size_t)b*PLP*PC);
    for (int e = t; e < 18*18*6; e += 64) {
        int pos = e / 6, k = e % 6;
        int r = pos / 18, cl = pos % 18;
        int gX = X0 + r, gY = Y0 + cl;
        float4 v = {0.f,0.f,0.f,0.f};
        if (gX >= 0 && gX < HP && gY >= 0 && gY < WP)
            v = pg[(size_t)(gX*WP + gY)*6 + k];
        *(float4*)(pt + pos*LSTR + k*4) = v;
    }
    __syncthreads();
    int Xg = tx*8 + x, Yg = ty*8 + y;
    const float* gq = g + (size_t)b*NB*PLP + (size_t)Xg*WP + Yg;
    float acc[PC];
    #pragma unroll
    for (int c = 0; c < PC; ++c) acc[c] = 0.f;
    for (int di = 0; di < KF; ++di) {
        const float* prow = pt + (x+di)*18*LSTR + y*LSTR;
        #pragma unroll
        for (int dj = 0; dj < KF; ++dj) {
            float gv = gq[(size_t)(di*KF + dj)*PLP];
            const float4* sp = (const float4*)(prow + dj*LSTR);
            float4 q0 = sp[0], q1 = sp[1], q2 = sp[2];
            float4 q3 = sp[3], q4 = sp[4], q5 = sp[5];
            acc[0]  = fmaf(gv, q0.x, acc[0]);  acc[1]  = fmaf(gv, q0.y, acc[1]);
            acc[2]  = fmaf(gv, q0.z, acc[2]);  acc[3]  = fmaf(gv, q0.w, acc[3]);
            acc[4]  = fmaf(gv, q1.x, acc[4]);  acc[5]  = fmaf(gv, q1.y, acc[5]);
            acc[6]  = fmaf(gv, q1.z, acc[6]);  acc[7]  = fmaf(gv, q1.w, acc[7]);
            acc[8]  = fmaf(gv, q2.x, acc[8]);  acc[9]  = fmaf(gv, q2.y, acc[9]);
            acc[10] = fmaf(gv, q2.z, acc[10]); acc[11] = fmaf(gv, q2.w, acc[11]);
            acc[12] = fmaf(gv, q3.x, acc[12]); acc[13] = fmaf(gv, q3.y, acc[13]);
            acc[14] = fmaf(gv, q3.z, acc[14]); acc[15] = fmaf(gv, q3.w, acc[15]);
            acc[16] = fmaf(gv, q4.x, acc[16]); acc[17] = fmaf(gv, q4.y, acc[17]);
            acc[18] = fmaf(gv, q4.z, acc[18]); acc[19] = fmaf(gv, q4.w, acc[19]);
            acc[20] = fmaf(gv, q5.x, acc[20]);
        }
    }
    float* mb = msg + (size_t)b*CC*PLP + (size_t)Xg*WP + Yg;
    #pragma unroll
    for (int c = 0; c < CC; ++c)
        mb[(size_t)c*PLP] = acc[c];
}

// bilinear 4x upsample of msg + 0.8*lg + 0.2*mu; iters 0..3: softmax + 4x4
// pool -> packed p; last iter: write fp32 pred. 2 pixels per thread.
// grid (16, 32, BB): block covers 16 rows x 32 cols.
__global__ __launch_bounds__(256) void combine_k(const float* __restrict__ msg,
                                                 const float* __restrict__ unary,
                                                 const float* __restrict__ weight,
                                                 float* __restrict__ pnew,
                                                 float* __restrict__ pred,
                                                 int last) {
    int b = blockIdx.z, tx = blockIdx.y, ty = blockIdx.x;
    int t = threadIdx.x;
    __shared__ float ms[CC][6][10];
    const float* mb = msg + (size_t)b*CC*PLP;
    for (int e = t; e < CC*60; e += 256) {
        int c = e / 60, rr = (e / 10) % 6, cl = e % 10;
        int gX = tx*4 - 1 + rr; gX = gX < 0 ? 0 : (gX > HP-1 ? HP-1 : gX);
        int gY = ty*8 - 1 + cl; gY = gY < 0 ? 0 : (gY > WP-1 ? WP-1 : gY);
        ms[c][rr][cl] = mb[(size_t)c*PLP + gX*WP + gY];
    }
    __syncthreads();
    int row = t >> 4, c2 = t & 15;
    int x = tx*16 + row, y = ty*32 + 2*c2;
    size_t base = (size_t)b*CC*PLF + (size_t)x*WW + y;
    // bilinear: fx per (x%4): {0.625, 0.875, 0.125, 0.375}
    int rs = row & 3, q = row >> 2;
    float fx = (rs == 0) ? 0.625f : (rs == 1) ? 0.875f : (rs == 2) ? 0.125f : 0.375f;
    int i0 = q + (rs >> 1);
    int cs0 = (2*c2) & 3;                    // 0 or 2; pixel pair shares j0
    int qc  = (2*c2) >> 2;
    float fya = (cs0 == 0) ? 0.625f : 0.125f;
    float fyb = (cs0 == 0) ? 0.875f : 0.375f;
    int j0 = qc + (cs0 >> 1);
    float gx0 = 1.f - fx;
    float wt = weight[0], uw = 1.f - wt;     // UNARY_WEIGHT = 1.0
    float va[CC], vb[CC];
    float ma = -1e30f, mbx = -1e30f;
    #pragma unroll
    for (int c = 0; c < CC; ++c) {
        float2 u = *(const float2*)(unary + base + (size_t)c*PLF);
        va[c] = u.x; vb[c] = u.y;
        ma = fmaxf(ma, u.x); mbx = fmaxf(mbx, u.y);
    }
    float sa = 0.f, sb = 0.f;
    #pragma unroll
    for (int c = 0; c < CC; ++c) { sa += expf(va[c]-ma); sb += expf(vb[c]-mbx); }
    float lsa = ma + logf(sa), lsb = mbx + logf(sb);
    #pragma unroll
    for (int c = 0; c < CC; ++c) {
        float m00 = ms[c][i0][j0],   m01 = ms[c][i0][j0+1];
        float m10 = ms[c][i0+1][j0], m11 = ms[c][i0+1][j0+1];
        float ca = gx0*m00 + fx*m10;         // column j0 blended in x
        float cb = gx0*m01 + fx*m11;         // column j0+1 blended in x
        float mua = (1.f-fya)*ca + fya*cb;
        float mub = (1.f-fyb)*ca + fyb*cb;
        va[c] = uw*(va[c]-lsa) + wt*mua;
        vb[c] = uw*(vb[c]-lsb) + wt*mub;
    }
    if (last) {
        #pragma unroll
        for (int c = 0; c < CC; ++c) {
            float2 o; o.x = va[c]; o.y = vb[c];
            *(float2*)(pred + base + (size_t)c*PLF) = o;
        }
    } else {
        float mma = -1e30f, mmb = -1e30f;
        #pragma unroll
        for (int c = 0; c < CC; ++c) { mma = fmaxf(mma, va[c]); mmb = fmaxf(mmb, vb[c]); }
        float ssa = 0.f, ssb = 0.f;
        #pragma unroll
        for (int c = 0; c < CC; ++c) {
            va[c] = expf(va[c]-mma); ssa += va[c];
            vb[c] = expf(vb[c]-mmb); ssb += vb[c];
        }
        float ia = 1.f/ssa, ib = 1.f/ssb;
        float out[PC];
        #pragma unroll
        for (int c = 0; c < PC; ++c) out[c] = 0.f;
        #pragma unroll
        for (int c = 0; c < CC; ++c) {
            float sm = va[c]*ia + vb[c]*ib;
            sm += __shfl_xor(sm, 1);
            sm += __shfl_xor(sm, 16);
            sm += __shfl_xor(sm, 32);
            out[c] = sm * (1.f/16.f);
        }
        int lane = t & 63;
        if ((lane & 49) == 0) {
            int X = tx*4 + (t >> 6), Y = ty*8 + (c2 >> 1);
            float4* dst = (float4*)(pnew + ((size_t)(b*HP + X)*WP + Y)*PC);
            const float4* src = (const float4*)out;
            dst[0]=src[0]; dst[1]=src[1]; dst[2]=src[2];
            dst[3]=src[3]; dst[4]=src[4]; dst[5]=src[5];
        }
    }
}

extern "C" void kernel_launch(void* const* d_in, const int* in_sizes, int n_in,
                              void* d_out, int out_size, void* d_ws, size_t ws_size,
                              hipStream_t stream) {
    const float* unary      = (const float*)d_in[0];
    const float* img        = (const float*)d_in[1];
    const float* pos_sdims  = (const float*)d_in[2];
    const float* col_schan  = (const float*)d_in[3];
    const float* pos_compat = (const float*)d_in[4];
    const float* col_compat = (const float*)d_in[5];
    const float* weight     = (const float*)d_in[6];
    float* pred = (float*)d_out;
    float* ws   = (float*)d_ws;

    size_t o = 0;
    float* cf  = ws + o;  o += (size_t)BB*3*PLP;     // 0.4 MB
    float* g   = ws + o;  o += (size_t)BB*NB*PLP;    // 15.9 MB
    float* msg = ws + o;  o += (size_t)BB*CC*PLP;    // 2.75 MB
    float* pA  = ws + o;  o += (size_t)BB*PLP*PC;    // 3.1 MB packed
    float* pB  = ws + o;
    float* pbuf[2] = {pA, pB};

    const int TB = 256;
    hipLaunchKernelGGL(pool_img_k, dim3((BB*3*PLP+TB-1)/TB), dim3(TB), 0, stream,
                       img, col_schan, cf);
    hipLaunchKernelGGL(gauss_k, dim3((BB*NB*PLP+TB-1)/TB), dim3(TB), 0, stream,
                       cf, pos_sdims, pos_compat, col_compat, g);
    hipLaunchKernelGGL(init_p_k, dim3(16, 32, BB), dim3(256), 0, stream,
                       unary, pA);
    for (int it = 0; it < NITER; ++it) {
        hipLaunchKernelGGL(msg_k, dim3(16, 16, BB), dim3(64), 0, stream,
                           g, pbuf[it & 1], msg);
        hipLaunchKernelGGL(combine_k, dim3(16, 32, BB), dim3(256), 0, stream,
                           msg, unary, weight, pbuf[(it + 1) & 1],
                           pred, (it == NITER-1) ? 1 : 0);
    }
}